// Round 10
// baseline (211.243 us; speedup 1.0000x reference)
//
#include <hip/hip_runtime.h>

#define SGRID 28
#define NBATCH 1024
constexpr int CELLS = NBATCH * SGRID * SGRID;   // 802816
constexpr int CPB   = 256;                      // cells per block (64 per wave)
constexpr int NBLK  = CELLS / CPB;              // 3136
constexpr float L_COORD = 5.0f;
constexpr float L_NOOBJ = 0.5f;

// Flat-stream kernel: pred is read as flat float2 (unit stride). For element
// e: cell=e/15, pos=e%15. pos<5 (box cols 0..9) -> ds_write to a wave-private
// 40B/cell slab (only transposed data). pos>=5 (cls cols 10..29) -> consumed
// immediately against tcls[cell*10+pos-5] (addresses strictly increasing
// across active lanes -> coalesced), mask via __shfl. No __syncthreads in the
// hot path (same-wave DS ordering, verified R6/R9). LDS 20.5KB (was 31KB),
// launch_bounds(256,6) -> 24 waves/CU floor (measured was ~12).
__global__ __launch_bounds__(256, 6) void yolo_main(
    const float* __restrict__ pred,      // CELLS*30
    const float* __restrict__ tboxes,    // CELLS*4
    const float* __restrict__ tcls,     // CELLS*20
    const int*   __restrict__ objmap,    // CELLS
    float4* __restrict__ partials)       // NBLK partials {reg, cobj, nbj, cls}
{
    __shared__ float2 sbox[4][64 * 10];      // 4 waves x 5120 B (box cols only)
    __shared__ float  sred[4][4];

    const int tid   = threadIdx.x;
    const int lane  = tid & 63;
    const int wid   = tid >> 6;
    const int wbase = blockIdx.x * CPB + wid * 64;   // wave's first cell

    const float2* pred2 = reinterpret_cast<const float2*>(pred);
    const float2* tcls2 = reinterpret_cast<const float2*>(tcls);
    const float4* tb4   = reinterpret_cast<const float4*>(tboxes);

    float2* sb = sbox[wid];
    const float invS = 1.0f / SGRID;

    // ---- own-cell loads (mask needed early for shfl) ----
    const float4 tbv = tb4[wbase + lane];
    const int    om  = objmap[wbase + lane];
    const float  fm  = om ? 1.f : 0.f;

    // ---- flat pred window: float2 indices [15*wbase, 15*wbase+960) ----
    const unsigned e0 = 15u * (unsigned)wbase + (unsigned)lane;
    float2 P[15];
    #pragma unroll
    for (int i = 0; i < 15; ++i) P[i] = pred2[e0 + 64u * i];

    // ---- element-flat processing: box f2 -> LDS, cls f2 -> immediate fma ----
    float clsv = 0.f;
    #pragma unroll
    for (int i = 0; i < 15; ++i) {
        unsigned e    = e0 + 64u * i;
        unsigned cell = e / 15u;                 // magic-mul division
        unsigned pos  = e - cell * 15u;
        unsigned cl   = cell - (unsigned)wbase;  // [0,64) within wave
        float mk = __shfl(fm, (int)cl, 64);      // all lanes active here
        if (pos < 5u) {
            sb[cl * 10u + pos] = P[i];
        } else {
            float2 t = tcls2[(size_t)cell * 10u + (pos - 5u)];
            float d0 = P[i].x - t.x, d1 = P[i].y - t.y;
            clsv += mk * (d0 * d0 + d1 * d1);
        }
    }
    // Same-wave DS ordering: all box writes above retire before reads below
    // (in-order DS pipe per wave; compiler inserts the lgkmcnt).

    // ---- per-cell box math (lane = cell; 10 floats from wave slab) ----
    float q[10];
    #pragma unroll
    for (int k = 0; k < 5; ++k) {
        float2 v = sb[lane * 10 + k];
        q[2 * k] = v.x; q[2 * k + 1] = v.y;
    }

    float reg, cobj, nbj;
    {
        float tx = tbv.x * invS, ty = tbv.y * invS;
        float thw = 0.5f * tbv.z, thh = 0.5f * tbv.w;
        float tx1 = tx - thw, ty1 = ty - thh, tx2 = tx + thw, ty2 = ty + thh;
        float ta = (tx2 - tx1) * (ty2 - ty1);

        float bx1[2], by1[2], bx2[2], by2[2], bcf[2], biou[2];
        #pragma unroll
        for (int b = 0; b < 2; ++b) {
            float cx = q[b*5+0] * invS, cy = q[b*5+1] * invS;
            float hw = 0.5f * q[b*5+2], hh = 0.5f * q[b*5+3];
            float x1 = cx - hw, y1 = cy - hh, x2 = cx + hw, y2 = cy + hh;
            bx1[b] = x1; by1[b] = y1; bx2[b] = x2; by2[b] = y2;
            bcf[b] = q[b*5+4];
            float ltx = fmaxf(x1, tx1), lty = fmaxf(y1, ty1);
            float rbx = fminf(x2, tx2), rby = fminf(y2, ty2);
            float wi = fmaxf(rbx - ltx, 0.f), hi = fmaxf(rby - lty, 0.f);
            float inter = wi * hi;
            float a1 = (x2 - x1) * (y2 - y1);
            biou[b] = inter / (a1 + ta - inter);
        }
        int sel = (biou[1] > biou[0]) ? 1 : 0;   // strict '>' == first-max tie-break
        float best_iou = biou[sel];
        bool valid = best_iou > 0.f;
        float bbx1 = valid ? bx1[sel] : 0.f;
        float bby1 = valid ? by1[sel] : 0.f;
        float bbx2 = valid ? bx2[sel] : 0.f;
        float bby2 = valid ? by2[sel] : 0.f;
        float bcfs = valid ? bcf[sel] : 0.f;
        best_iou   = valid ? best_iou : 0.f;

        float dx = bbx1 - tx1, dy = bby1 - ty1;
        float lxy = dx * dx + dy * dy;
        float swx = bbx2 > 0.f ? sqrtf(bbx2) : 0.f;
        float swy = bby2 > 0.f ? sqrtf(bby2) : 0.f;
        float twx = tx2  > 0.f ? sqrtf(tx2)  : 0.f;
        float twy = ty2  > 0.f ? sqrtf(ty2)  : 0.f;
        float dwx = swx - twx, dwy = swy - twy;
        reg = fm * (lxy + dwx * dwx + dwy * dwy);

        float c0 = q[4], c1 = q[9];
        nbj = (1.f - fm) * (c0 * c0 + c1 * c1);

        float dcf = bcfs - best_iou;
        cobj = fm * dcf * dcf;
    }

    // ---- reduction: wave64 shuffle, then cross-wave via LDS ----
    #pragma unroll
    for (int off = 32; off > 0; off >>= 1) {
        reg  += __shfl_down(reg,  off);
        cobj += __shfl_down(cobj, off);
        nbj  += __shfl_down(nbj,  off);
        clsv += __shfl_down(clsv, off);
    }
    if (lane == 0) {
        sred[wid][0] = reg; sred[wid][1] = cobj;
        sred[wid][2] = nbj; sred[wid][3] = clsv;
    }
    __syncthreads();
    if (tid == 0) {
        float4 s;
        s.x = sred[0][0] + sred[1][0] + sred[2][0] + sred[3][0];
        s.y = sred[0][1] + sred[1][1] + sred[2][1] + sred[3][1];
        s.z = sred[0][2] + sred[1][2] + sred[2][2] + sred[3][2];
        s.w = sred[0][3] + sred[1][3] + sred[2][3] + sred[3][3];
        partials[blockIdx.x] = s;
    }
}

__global__ __launch_bounds__(256) void yolo_finalize(
    const float4* __restrict__ partials, float* __restrict__ out)
{
    float4 s = {0.f, 0.f, 0.f, 0.f};
    for (int b = threadIdx.x; b < NBLK; b += 256) {
        float4 v = partials[b];
        s.x += v.x; s.y += v.y; s.z += v.z; s.w += v.w;
    }
    #pragma unroll
    for (int off = 32; off > 0; off >>= 1) {
        s.x += __shfl_down(s.x, off);
        s.y += __shfl_down(s.y, off);
        s.z += __shfl_down(s.z, off);
        s.w += __shfl_down(s.w, off);
    }
    __shared__ float4 sw[4];
    int wave = threadIdx.x >> 6, lane = threadIdx.x & 63;
    if (lane == 0) sw[wave] = s;
    __syncthreads();
    if (threadIdx.x == 0) {
        float r = 0.f, c = 0.f, n = 0.f, cl = 0.f;
        #pragma unroll
        for (int w = 0; w < 4; ++w) {
            r += sw[w].x; c += sw[w].y; n += sw[w].z; cl += sw[w].w;
        }
        const float invN = 1.0f / NBATCH;
        float reg_l  = L_COORD * r * invN;
        float cobj_l = c * invN;
        float nbj_l  = L_NOOBJ * n * invN;
        float cls_l  = 2.0f * cl * invN;
        out[0] = cls_l + nbj_l + reg_l + cobj_l;
        out[1] = reg_l;
        out[2] = cobj_l;
        out[3] = nbj_l;
        out[4] = cls_l;
    }
}

extern "C" void kernel_launch(void* const* d_in, const int* in_sizes, int n_in,
                              void* d_out, int out_size, void* d_ws, size_t ws_size,
                              hipStream_t stream) {
    const float* pred   = (const float*)d_in[0];
    const float* tboxes = (const float*)d_in[1];
    const float* tcls   = (const float*)d_in[2];
    const int*   objmap = (const int*)d_in[3];
    float4* partials = (float4*)d_ws;
    float*  out      = (float*)d_out;

    yolo_main<<<NBLK, 256, 0, stream>>>(pred, tboxes, tcls, objmap, partials);
    yolo_finalize<<<1, 256, 0, stream>>>(partials, out);
}

// Round 13
// 200.447 us; speedup vs baseline: 1.0539x; 1.0539x over previous
//
#include <hip/hip_runtime.h>

#define SGRID 28
#define NBATCH 1024
constexpr int CELLS = NBATCH * SGRID * SGRID;   // 802816
constexpr int CPB   = 256;                      // cells per block (64 per wave)
constexpr int NBLK  = CELLS / CPB;              // 3136
constexpr float L_COORD = 5.0f;
constexpr float L_NOOBJ = 0.5f;

// R9 structure (wave-private slab, zero hot-path barriers, 66.8us) with ONE
// change: tcls float4 loads are predicated on the covering cell's mask.
// ~50% of cells have mask=0 -> their cls term is exactly 0; skipping the
// load cuts ~22MB (~12.5%) of the 176.6MB consumption stream. Exec-masked
// lanes issue no address -> TA fetches fewer granules. Bit-exact: skipped
// lanes contribute mk*(pc-0)^2 = 0.0f, same as before.
__global__ __launch_bounds__(256) void yolo_main(
    const float* __restrict__ pred,      // CELLS*30
    const float* __restrict__ tboxes,    // CELLS*4
    const float* __restrict__ tcls,      // CELLS*20
    const int*   __restrict__ objmap,    // CELLS
    float4* __restrict__ partials)       // NBLK partials {reg, cobj, nbj, cls}
{
    __shared__ float spred[4][64 * 30];      // 4 waves x 7680 B, wave-private
    __shared__ float sred[4][4];

    const int tid   = threadIdx.x;
    const int lane  = tid & 63;
    const int wid   = tid >> 6;
    const int wbase = blockIdx.x * CPB + wid * 64;

    const float2* pred2 = reinterpret_cast<const float2*>(pred);
    const float4* tb4   = reinterpret_cast<const float4*>(tboxes);
    const float4* tc4   = reinterpret_cast<const float4*>(tcls);

    float*  swave = &spred[wid][0];
    float2* sp2   = reinterpret_cast<float2*>(swave);

    const float invS = 1.0f / SGRID;

    // ---- load burst: pred slab (unit-stride float2), own-cell tb + mask ----
    float2 P[15];
    const float2* pp = pred2 + (size_t)wbase * 15;
    #pragma unroll
    for (int i = 0; i < 15; ++i) P[i] = pp[lane + 64 * i];

    const float4 tbv = tb4[wbase + lane];
    const int    om  = objmap[wbase + lane];
    const float  fm  = om ? 1.f : 0.f;

    // ---- masks for this lane's 5 tcls elements, then predicated burst ----
    const float4* tcb = tc4 + (size_t)wbase * 5;
    float  mk[5];
    float4 tcv[5];
    #pragma unroll
    for (int i = 0; i < 5; ++i) {
        int e    = lane + 64 * i;                // [0, 320) float4-groups
        int cell = e / 5;                        // [0, 64) local cell
        mk[i] = __shfl(fm, cell, 64);
        tcv[i] = make_float4(0.f, 0.f, 0.f, 0.f);
        if (mk[i] != 0.f) tcv[i] = tcb[e];       // exec-masked: no addr issued
    }

    // ---- stage pred slab into wave-private LDS (transpose to per-cell) ----
    #pragma unroll
    for (int i = 0; i < 15; ++i) sp2[lane + 64 * i] = P[i];

    // ---- per-cell box math (lane = cell, LDS stride 30 floats) ----
    const float* q = swave + lane * 30;

    float reg, cobj, nbj, clsv = 0.f;
    {
        float tx = tbv.x * invS, ty = tbv.y * invS;
        float thw = 0.5f * tbv.z, thh = 0.5f * tbv.w;
        float tx1 = tx - thw, ty1 = ty - thh, tx2 = tx + thw, ty2 = ty + thh;
        float ta = (tx2 - tx1) * (ty2 - ty1);

        float bx1[2], by1[2], bx2[2], by2[2], bcf[2], biou[2];
        #pragma unroll
        for (int b = 0; b < 2; ++b) {
            float cx = q[b*5+0] * invS, cy = q[b*5+1] * invS;
            float hw = 0.5f * q[b*5+2], hh = 0.5f * q[b*5+3];
            float x1 = cx - hw, y1 = cy - hh, x2 = cx + hw, y2 = cy + hh;
            bx1[b] = x1; by1[b] = y1; bx2[b] = x2; by2[b] = y2;
            bcf[b] = q[b*5+4];
            float ltx = fmaxf(x1, tx1), lty = fmaxf(y1, ty1);
            float rbx = fminf(x2, tx2), rby = fminf(y2, ty2);
            float wi = fmaxf(rbx - ltx, 0.f), hi = fmaxf(rby - lty, 0.f);
            float inter = wi * hi;
            float a1 = (x2 - x1) * (y2 - y1);
            biou[b] = inter / (a1 + ta - inter);
        }
        int sel = (biou[1] > biou[0]) ? 1 : 0;   // strict '>' == first-max tie-break
        float best_iou = biou[sel];
        bool valid = best_iou > 0.f;
        float bbx1 = valid ? bx1[sel] : 0.f;
        float bby1 = valid ? by1[sel] : 0.f;
        float bbx2 = valid ? bx2[sel] : 0.f;
        float bby2 = valid ? by2[sel] : 0.f;
        float bcfs = valid ? bcf[sel] : 0.f;
        best_iou   = valid ? best_iou : 0.f;

        float dx = bbx1 - tx1, dy = bby1 - ty1;
        float lxy = dx * dx + dy * dy;
        float swx = bbx2 > 0.f ? sqrtf(bbx2) : 0.f;
        float swy = bby2 > 0.f ? sqrtf(bby2) : 0.f;
        float twx = tx2  > 0.f ? sqrtf(tx2)  : 0.f;
        float twy = ty2  > 0.f ? sqrtf(ty2)  : 0.f;
        float dwx = swx - twx, dwy = swy - twy;
        reg = fm * (lxy + dwx * dwx + dwy * dwy);

        float c0 = q[4], c1 = q[9];
        nbj = (1.f - fm) * (c0 * c0 + c1 * c1);

        float dcf = bcfs - best_iou;
        cobj = fm * dcf * dcf;
    }

    // ---- cls loss: unconditional math (tcv=0 where masked -> exact 0) ----
    #pragma unroll
    for (int i = 0; i < 5; ++i) {
        int e    = lane + 64 * i;
        int cell = e / 5;
        int c0i  = (e - cell * 5) * 4;
        const float* pc = swave + cell * 30 + 10 + c0i;
        float4 tv = tcv[i];
        float d0 = pc[0] - tv.x, d1 = pc[1] - tv.y;
        float d2 = pc[2] - tv.z, d3 = pc[3] - tv.w;
        clsv += mk[i] * (d0 * d0 + d1 * d1 + d2 * d2 + d3 * d3);
    }

    // ---- reduction: wave64 shuffle, then cross-wave via LDS ----
    #pragma unroll
    for (int off = 32; off > 0; off >>= 1) {
        reg  += __shfl_down(reg,  off);
        cobj += __shfl_down(cobj, off);
        nbj  += __shfl_down(nbj,  off);
        clsv += __shfl_down(clsv, off);
    }
    if (lane == 0) {
        sred[wid][0] = reg; sred[wid][1] = cobj;
        sred[wid][2] = nbj; sred[wid][3] = clsv;
    }
    __syncthreads();
    if (tid == 0) {
        float4 s;
        s.x = sred[0][0] + sred[1][0] + sred[2][0] + sred[3][0];
        s.y = sred[0][1] + sred[1][1] + sred[2][1] + sred[3][1];
        s.z = sred[0][2] + sred[1][2] + sred[2][2] + sred[3][2];
        s.w = sred[0][3] + sred[1][3] + sred[2][3] + sred[3][3];
        partials[blockIdx.x] = s;
    }
}

__global__ __launch_bounds__(256) void yolo_finalize(
    const float4* __restrict__ partials, float* __restrict__ out)
{
    float4 s = {0.f, 0.f, 0.f, 0.f};
    for (int b = threadIdx.x; b < NBLK; b += 256) {
        float4 v = partials[b];
        s.x += v.x; s.y += v.y; s.z += v.z; s.w += v.w;
    }
    #pragma unroll
    for (int off = 32; off > 0; off >>= 1) {
        s.x += __shfl_down(s.x, off);
        s.y += __shfl_down(s.y, off);
        s.z += __shfl_down(s.z, off);
        s.w += __shfl_down(s.w, off);
    }
    __shared__ float4 sw[4];
    int wave = threadIdx.x >> 6, lane = threadIdx.x & 63;
    if (lane == 0) sw[wave] = s;
    __syncthreads();
    if (threadIdx.x == 0) {
        float r = 0.f, c = 0.f, n = 0.f, cl = 0.f;
        #pragma unroll
        for (int w = 0; w < 4; ++w) {
            r += sw[w].x; c += sw[w].y; n += sw[w].z; cl += sw[w].w;
        }
        const float invN = 1.0f / NBATCH;
        float reg_l  = L_COORD * r * invN;
        float cobj_l = c * invN;
        float nbj_l  = L_NOOBJ * n * invN;
        float cls_l  = 2.0f * cl * invN;
        out[0] = cls_l + nbj_l + reg_l + cobj_l;
        out[1] = reg_l;
        out[2] = cobj_l;
        out[3] = nbj_l;
        out[4] = cls_l;
    }
}

extern "C" void kernel_launch(void* const* d_in, const int* in_sizes, int n_in,
                              void* d_out, int out_size, void* d_ws, size_t ws_size,
                              hipStream_t stream) {
    const float* pred   = (const float*)d_in[0];
    const float* tboxes = (const float*)d_in[1];
    const float* tcls   = (const float*)d_in[2];
    const int*   objmap = (const int*)d_in[3];
    float4* partials = (float4*)d_ws;
    float*  out      = (float*)d_out;

    yolo_main<<<NBLK, 256, 0, stream>>>(pred, tboxes, tcls, objmap, partials);
    yolo_finalize<<<1, 256, 0, stream>>>(partials, out);
}